// Round 12
// baseline (404.037 us; speedup 1.0000x reference)
//
#include <hip/hip_runtime.h>
#include <stdint.h>

// ---------------------------------------------------------------------------
// TransformerBlock on MI355X (gfx950). Runtime dtype detection (fp32 vs bf16
// inputs), bf16-MFMA internal compute, fp32 accumulation + fp32 residual path.
// B=2 S=2048 D=1024 H=16 K=64 MLP=4096; tokens M = 4096.
// R14: attn spill fix (gfx950 UNIFIED VGPR/AGPR file; launch_bounds caps
// TOTAL regs) -> 414. R16: gload_lds+dbuf 2-phase gemms -> 410. R17/R18:
// MLP-up on 256^2 4-phase counted-vmcnt template (final-iter vmcnt race
// fixed) -> 405.4. R19: MLP-down split-K=4 on the same template + fused
// reduce (partials in dead ws buffers) -> 403.3.
// R20: attn_part was top (55.3us; VALU 34%, MFMA 19%, HBM 12% -> pipes idle
// ~47%; 2-barrier-per-step structure). Apply T14 async-STAGE split +
// single-barrier double-buffer: K/V LDS tiles x2, issue next-step global
// loads BEFORE compute, ds_write to buf^1 AFTER compute, ONE barrier/step.
// Load latency hides under the full QK/softmax/PV phase. Layouts unchanged
// (reg-staged writes keep pad/permute). LDS 71.7KB -> still 2 blocks/CU;
// reg peak ~90 <= 128 cap. Everything else frozen.
// ---------------------------------------------------------------------------

typedef unsigned short u16;
typedef __bf16 bf16x8 __attribute__((ext_vector_type(8)));
typedef __bf16 bf16x4 __attribute__((ext_vector_type(4)));
typedef __bf16 bf16x2 __attribute__((ext_vector_type(2)));
typedef short  s16x4  __attribute__((ext_vector_type(4)));
typedef float  f32x4  __attribute__((ext_vector_type(4)));

#define QSCALE 0.18033688011112042f   // (1/sqrt(64)) * log2(e): softmax via exp2

__device__ __forceinline__ float bf2f(unsigned int u) {
  union { unsigned int u; float f; } v; v.u = u << 16; return v.f;
}
__device__ __forceinline__ u16 f2bf(float f) {
  union { float f; unsigned int u; } v; v.f = f;
  unsigned int r = v.u + 0x7FFFu + ((v.u >> 16) & 1u);   // RNE
  return (u16)(r >> 16);
}
__device__ __forceinline__ unsigned pkbf(float lo, float hi) {
#if __has_builtin(__builtin_amdgcn_cvt_pk_bf16_f32)
  bf16x2 t = __builtin_amdgcn_cvt_pk_bf16_f32(lo, hi);
  return __builtin_bit_cast(unsigned, t);
#else
  return (unsigned)f2bf(lo) | ((unsigned)f2bf(hi) << 16);
#endif
}
__device__ __forceinline__ float loadf(const void* p, size_t i, int isf) {
  return isf ? ((const float*)p)[i] : bf2f(((const u16*)p)[i]);
}

// async global->LDS, 16B per lane; LDS dest must be wave-uniform base
// (HW writes base + lane*16), global src is per-lane.
__device__ __forceinline__ void load_lds16(const u16* g, u16* l) {
  __builtin_amdgcn_global_load_lds(
      (const __attribute__((address_space(1))) void*)g,
      (__attribute__((address_space(3))) void*)l, 16, 0, 0);
}

// 16x16x16 bf16 MFMA wrapper
__device__ __forceinline__ f32x4 mfma16(s16x4 a, s16x4 b, f32x4 c) {
#if __has_builtin(__builtin_amdgcn_mfma_f32_16x16x16_bf16)
  return __builtin_amdgcn_mfma_f32_16x16x16_bf16(
      __builtin_bit_cast(bf16x4, a), __builtin_bit_cast(bf16x4, b), c, 0, 0, 0);
#else
  return __builtin_amdgcn_mfma_f32_16x16x16bf16_1k(a, b, c, 0, 0, 0);
#endif
}

// ---------------------------------------------------------------------------
__global__ __launch_bounds__(256) void detect_dtype(
    const unsigned int* __restrict__ x, int* __restrict__ flag) {
  __shared__ int cnt;
  if (threadIdx.x == 0) cnt = 0;
  __syncthreads();
  int c = 0;
  for (int i = threadIdx.x; i < 512; i += 256) {
    unsigned int e = (x[i] >> 23) & 0xFFu;
    if (e >= 97u && e <= 157u) c++;
  }
  atomicAdd(&cnt, c);
  __syncthreads();
  if (threadIdx.x == 0) *flag = (cnt > 384) ? 1 : 0;
}

// ---------------------------------------------------------------------------
// Tiled transposes: 64x64 tiles through LDS (stride-65 pad -> 2-way = free).
// ---------------------------------------------------------------------------
__global__ __launch_bounds__(256) void pack_qkv_tiled(
    const int* __restrict__ flagp,
    const void* __restrict__ Wq, const void* __restrict__ Wk, const void* __restrict__ Wv,
    u16* __restrict__ WT) {
  __shared__ float t[64][65];
  const int isf = *flagp;
  const int tid = threadIdx.x;
  const int mh = blockIdx.y;            // mat*16 + h
  const int mat = mh >> 4, h = mh & 15;
  const int d0 = blockIdx.x << 6;       // d-tile
  const void* src = (mat == 0) ? Wq : (mat == 1) ? Wk : Wv;
  const float scale = (mat == 0) ? QSCALE : 1.f;
  const int lane = tid & 63, rr = tid >> 6;
  const size_t sbase = ((size_t)h << 16) + lane;
#pragma unroll
  for (int i = 0; i < 16; i++) {
    int d = i * 4 + rr;
    t[d][lane] = loadf(src, sbase + (size_t)(d0 + d) * 64, isf) * scale;
  }
  __syncthreads();
#pragma unroll
  for (int i = 0; i < 16; i++) {
    int k = i * 4 + rr;
    WT[((size_t)((mat << 10) + (h << 6) + k) << 10) + d0 + lane] = f2bf(t[lane][k]);
  }
}

__global__ __launch_bounds__(256) void transpose_tiled(
    const int* __restrict__ flagp, const void* __restrict__ src,
    u16* __restrict__ dst, int R, int C) {
  __shared__ float t[64][65];
  const int isf = *flagp;
  const int tid = threadIdx.x;
  const int c0 = blockIdx.x << 6, r0 = blockIdx.y << 6;
  const int lane = tid & 63, rr = tid >> 6;
#pragma unroll
  for (int i = 0; i < 16; i++) {
    int r = i * 4 + rr;
    t[r][lane] = loadf(src, (size_t)(r0 + r) * C + c0 + lane, isf);
  }
  __syncthreads();
#pragma unroll
  for (int i = 0; i < 16; i++) {
    int c = i * 4 + rr;
    dst[(size_t)(c0 + c) * R + r0 + lane] = f2bf(t[lane][c]);
  }
}

__global__ __launch_bounds__(256) void pack_biases(
    const int* __restrict__ flagp,
    const void* bq, const void* bk, const void* bv,
    const void* bO, const void* bin, const void* bout,
    float* __restrict__ out) {
  const int isf = *flagp;
  int i = blockIdx.x * 256 + threadIdx.x;
  float v;
  if (i < 1024)      v = loadf(bq,   i,        isf) * QSCALE;
  else if (i < 2048) v = loadf(bk,   i - 1024, isf);
  else if (i < 3072) v = loadf(bv,   i - 2048, isf);
  else if (i < 4096) v = loadf(bO,   i - 3072, isf);
  else if (i < 8192) v = loadf(bin,  i - 4096, isf);
  else               v = loadf(bout, i - 8192, isf);
  out[i] = v;
}

// ---------------------------------------------------------------------------
template<int SRC>
__global__ __launch_bounds__(256) void ln_fwd(
    const int* __restrict__ flagp, const void* __restrict__ xin,
    const void* __restrict__ w, const void* __restrict__ b,
    u16* __restrict__ out) {
  const int isf = *flagp;
  const int row = blockIdx.x, tid = threadIdx.x;
  const int col = tid << 2;
  const size_t base = ((size_t)row << 10) + col;
  float v[4];
#pragma unroll
  for (int i = 0; i < 4; i++)
    v[i] = (SRC == 1) ? ((const float*)xin)[base + i] : loadf(xin, base + i, isf);
  float s  = v[0] + v[1] + v[2] + v[3];
  float ss = v[0]*v[0] + v[1]*v[1] + v[2]*v[2] + v[3]*v[3];
#pragma unroll
  for (int mk = 32; mk >= 1; mk >>= 1) {
    s  += __shfl_xor(s,  mk, 64);
    ss += __shfl_xor(ss, mk, 64);
  }
  __shared__ float red[8];
  if ((tid & 63) == 0) { red[tid >> 6] = s; red[4 + (tid >> 6)] = ss; }
  __syncthreads();
  float S  = red[0] + red[1] + red[2] + red[3];
  float SS = red[4] + red[5] + red[6] + red[7];
  float mean = S * (1.f / 1024.f);
  float var  = SS * (1.f / 1024.f) - mean * mean;
  float rstd = rsqrtf(var + 1e-5f);
  u16 e[4];
#pragma unroll
  for (int i = 0; i < 4; i++) {
    float wv = loadf(w, col + i, isf);
    float bv = loadf(b, col + i, isf);
    e[i] = f2bf((v[i] - mean) * rstd * wv + bv);
  }
  uint2 o;
  o.x = (unsigned)e[0] | ((unsigned)e[1] << 16);
  o.y = (unsigned)e[2] | ((unsigned)e[3] << 16);
  *(uint2*)(out + base) = o;
}

// ---------------------------------------------------------------------------
// R17/R18/R19: 256x256-tile 4-phase GEMM with counted vmcnt (m201 template).
// EPI=0: C = relu(A @ BT^T + bias) -> bf16, full K, grid (M/256)x(N/256)
//        XCD-striped (256 blocks @ MODE 1).
// EPI=1: fp32 partials, SPLIT-K/4: grid 16row x 4col x 4kc = 256 blocks;
//        block computes its 256x256 tile over K-chunk kc, stores raw acc
//        to pp[row*N+col] (pp selected from p0..p3 by kc). nt = K/256.
// 512 thr / 8 waves (2Mx4N); per-wave output 128x64 (acc[8][4] f32x4).
// LDS 128KB: [2 buf][4 unit][8192 u16]; unit = 256 rows x 32 k (A or BT).
// Swizzle: 16B chunk ^= (row>>1)&3, write via pre-swizzled global src,
// read via XOR on ds_read addr (both-sides involution).
// vmcnt ledger (verified R18): steady end-ph0 vmcnt(2) (final: vmcnt(0));
// end-ph3 vmcnt(4).
// ---------------------------------------------------------------------------
template<int EPI>
__global__ __launch_bounds__(512, 2) void gemm256(
    const u16* __restrict__ A, const u16* __restrict__ BT,
    const float* __restrict__ bias, u16* __restrict__ out,
    float* __restrict__ p0, float* __restrict__ p1,
    float* __restrict__ p2, float* __restrict__ p3,
    int M, int N, int K) {
  __shared__ __align__(16) u16 lds[65536];   // 128 KB
  const int tid = threadIdx.x, L = tid & 63, w = tid >> 6;
  const int m = L & 15, quad = L >> 4;
  const int bid = blockIdx.x;
  int by, bx, kstart, nt;
  float* pp = nullptr;
  if constexpr (EPI == 0) {
    const int xcd = bid & 7, s = bid >> 3;
    const int spx = (M >> 8) >> 3;          // row-tiles per XCD
    by = xcd * spx + (s % spx);
    bx = s / spx;
    kstart = 0; nt = K >> 6;
  } else {
    const int xcd = bid & 7, s = bid >> 3;  // 256 blocks: 2row x 4col x 4kc per XCD
    by = xcd * 2 + (s & 1);
    const int r2 = s >> 1;
    bx = r2 & 3;
    const int kc = r2 >> 2;
    kstart = kc * (K >> 2);
    nt = K >> 8;                            // (K/4)/64
    pp = kc == 0 ? p0 : kc == 1 ? p1 : kc == 2 ? p2 : p3;
  }
  const int row0 = by << 8, col0 = bx << 8;
  const int wrow = (w >> 2) << 7, wcol = (w & 3) << 6;

  f32x4 acc[8][4];
#pragma unroll
  for (int i = 0; i < 8; i++)
#pragma unroll
    for (int j = 0; j < 4; j++) acc[i][j] = f32x4{0.f, 0.f, 0.f, 0.f};

  // staging constants: lane covers (row = w*16 + L>>2 [+128], chunk L&3)
  const int srow = (w << 4) + (L >> 2);
  const int lc   = (L & 3) ^ ((srow >> 1) & 3);   // (+128 preserves (row>>1)&3)
  const int ldst = w << 9;                         // elems within half (w*512)

  // stage one 16KB unit (2 x gload_lds per thread) of tile at kcol0
  auto stageU = [&](const u16* __restrict__ src, int srcRow0, int kcol0,
                    int nb, int u) {
#pragma unroll
    for (int half = 0; half < 2; half++) {
      const u16* g = src + (size_t)(srcRow0 + srow + half * 128) * K + kcol0 + lc * 8;
      load_lds16(g, &lds[(nb << 15) + (u << 13) + (half << 12) + ldst]);
    }
  };
  // A-frags: 4 row-frags for row-half rh from k-half kh of buffer b
  auto rdA = [&](int b, int kh, int rh, bf16x8* af) {
#pragma unroll
    for (int i = 0; i < 4; i++) {
      int row = wrow + rh * 64 + i * 16 + m;
      int off = (b << 15) + ((kh << 1) << 13) + row * 32
              + ((quad * 8) ^ (((row >> 1) & 3) << 3));
      af[i] = *(const bf16x8*)&lds[off];
    }
  };
  auto rdB = [&](int b, int kh, bf16x8* bf) {
#pragma unroll
    for (int j = 0; j < 4; j++) {
      int row = wcol + j * 16 + m;
      int off = (b << 15) + (((kh << 1) | 1) << 13) + row * 32
              + ((quad * 8) ^ (((row >> 1) & 3) << 3));
      bf[j] = *(const bf16x8*)&lds[off];
    }
  };

  // prologue: tile 0 -> buf 0 (units p0..p3); retire p0,p1; leave p2,p3 in flight
  stageU(A,  row0, kstart,      0, 0);
  stageU(BT, col0, kstart,      0, 1);
  stageU(A,  row0, kstart + 32, 0, 2);
  stageU(BT, col0, kstart + 32, 0, 3);
  asm volatile("s_waitcnt vmcnt(4)" ::: "memory");
  __builtin_amdgcn_s_barrier();

  for (int t = 0; t < nt; ++t) {
    const int b = t & 1, nb = b ^ 1;
    const bool pf = (t + 1 < nt);
    const int k1c = kstart + ((t + 1) << 6);
    bf16x8 af[4], bf0[4], bf1[4];
    // ---- phase 0: k-half 0, rows 0-63; stage A-k0(t+1) ----
    rdA(b, 0, 0, af); rdB(b, 0, bf0);
    if (pf) stageU(A, row0, k1c, nb, 0);
    __builtin_amdgcn_s_setprio(1);
#pragma unroll
    for (int i = 0; i < 4; i++)
#pragma unroll
      for (int j = 0; j < 4; j++)
        acc[i][j] = __builtin_amdgcn_mfma_f32_16x16x32_bf16(af[i], bf0[j], acc[i][j], 0, 0, 0);
    __builtin_amdgcn_s_setprio(0);
    // R18 fix: steady vmcnt(2) retires t p2,p3 (keeps t+1 p0 in flight);
    // FINAL iter (no stage issued) must drain to 0 else B-k1 races phase 1.
    if (pf) { asm volatile("s_waitcnt vmcnt(2)" ::: "memory"); }
    else    { asm volatile("s_waitcnt vmcnt(0)" ::: "memory"); }
    __builtin_amdgcn_s_barrier();
    // ---- phase 1: k-half 1, rows 0-63; stage B-k0(t+1) ----
    rdA(b, 1, 0, af); rdB(b, 1, bf1);
    if (pf) stageU(BT, col0, k1c, nb, 1);
    __builtin_amdgcn_s_setprio(1);
#pragma unroll
    for (int i = 0; i < 4; i++)
#pragma unroll
      for (int j = 0; j < 4; j++)
        acc[i][j] = __builtin_amdgcn_mfma_f32_16x16x32_bf16(af[i], bf1[j], acc[i][j], 0, 0, 0);
    __builtin_amdgcn_s_setprio(0);
    __builtin_amdgcn_s_barrier();
    // ---- phase 2: k-half 0, rows 64-127 (bf0 reused); stage A-k1(t+1) ----
    rdA(b, 0, 1, af);
    if (pf) stageU(A, row0, k1c + 32, nb, 2);
    __builtin_amdgcn_s_setprio(1);
#pragma unroll
    for (int i = 0; i < 4; i++)
#pragma unroll
      for (int j = 0; j < 4; j++)
        acc[4 + i][j] = __builtin_amdgcn_mfma_f32_16x16x32_bf16(af[i], bf0[j], acc[4 + i][j], 0, 0, 0);
    __builtin_amdgcn_s_setprio(0);
    __builtin_amdgcn_s_barrier();
    // ---- phase 3: k-half 1, rows 64-127 (bf1 reused); stage B-k1(t+1) ----
    rdA(b, 1, 1, af);
    if (pf) stageU(BT, col0, k1c + 32, nb, 3);
    __builtin_amdgcn_s_setprio(1);
#pragma unroll
    for (int i = 0; i < 4; i++)
#pragma unroll
      for (int j = 0; j < 4; j++)
        acc[4 + i][j] = __builtin_amdgcn_mfma_f32_16x16x32_bf16(af[i], bf1[j], acc[4 + i][j], 0, 0, 0);
    __builtin_amdgcn_s_setprio(0);
    asm volatile("s_waitcnt vmcnt(4)" ::: "memory");   // retire t+1 p0,p1 (final: trivial)
    __builtin_amdgcn_s_barrier();
  }

  if constexpr (EPI == 0) {
    // epilogue: relu + bias -> bf16
#pragma unroll
    for (int j = 0; j < 4; j++) {
      const int col = col0 + wcol + j * 16 + m;
      const float bval = bias[col];
#pragma unroll
      for (int i = 0; i < 8; i++) {
        const int rowb = row0 + wrow + i * 16 + quad * 4;
#pragma unroll
        for (int r = 0; r < 4; r++)
          out[(size_t)(rowb + r) * N + col] = f2bf(fmaxf(acc[i][j][r] + bval, 0.f));
      }
    }
  } else {
    // epilogue: raw fp32 partials (bias/resid applied in reduce_sk)
#pragma unroll
    for (int j = 0; j < 4; j++) {
      const int col = col0 + wcol + j * 16 + m;
#pragma unroll
      for (int i = 0; i < 8; i++) {
        const int rowb = row0 + wrow + i * 16 + quad * 4;
#pragma unroll
        for (int r = 0; r < 4; r++)
          pp[(size_t)(rowb + r) * N + col] = acc[i][j][r];
      }
    }
  }
}

// ---------------------------------------------------------------------------
// R19: reduce split-K partials: out = resid + p0+p1+p2+p3 + bias, flagged
// dtype. 4 fp32 elems/thread, fully coalesced int4 loads.
// ---------------------------------------------------------------------------
__global__ __launch_bounds__(256) void reduce_sk(
    const int* __restrict__ flagp,
    const float* __restrict__ p0, const float* __restrict__ p1,
    const float* __restrict__ p2, const float* __restrict__ p3,
    const float* __restrict__ bias, const float* __restrict__ resid,
    void* __restrict__ out) {
  const int isf = *flagp;
  const size_t base = ((size_t)blockIdx.x * 256 + threadIdx.x) * 4;
  const int col = (int)(base & 1023);
  f32x4 a0 = *(const f32x4*)(p0 + base);
  f32x4 a1 = *(const f32x4*)(p1 + base);
  f32x4 a2 = *(const f32x4*)(p2 + base);
  f32x4 a3 = *(const f32x4*)(p3 + base);
  f32x4 rs = *(const f32x4*)(resid + base);
  f32x4 o;
#pragma unroll
  for (int i = 0; i < 4; i++)
    o[i] = (a0[i] + a1[i]) + (a2[i] + a3[i]) + bias[col + i] + rs[i];
  if (isf) {
    *(f32x4*)((float*)out + base) = o;
  } else {
    uint2 pk;
    pk.x = pkbf(o[0], o[1]);
    pk.y = pkbf(o[2], o[3]);
    *(uint2*)((u16*)out + base) = pk;
  }
}

// ---------------------------------------------------------------------------
// GEMM C[M,N] = A[M,K] @ BT[N,K]^T + bias. KW*256 threads. (R16 structure,
// used for MODES 2/4.) gload_lds + double-buffered LDS, one barrier/step.
// ---------------------------------------------------------------------------
template<int MODE, int TM, int KW>
__global__ __launch_bounds__(KW * 256) void gemm_bt(
    const int* __restrict__ flagp,
    const u16* __restrict__ A, const u16* __restrict__ BT,
    const float* __restrict__ bias, const void* __restrict__ resid,
    void* __restrict__ out, void* __restrict__ out2, void* __restrict__ out3,
    int M, int N, int K, int SHL) {
  constexpr int WR = TM / 32;          // row-frags per wave
  constexpr int ASZ = TM * 32;         // per-group-per-buffer LDS elems (u16)
  constexpr int BSZ = 128 * 32;
  constexpr int STAGE_B = KW * 2 * (ASZ + BSZ) * 2;    // dbuf, bytes
  constexpr int RED_B = (KW > 1) ? TM * 132 * 4 : 1;   // padded fp32 combine
  constexpr int SMEM_B = STAGE_B > RED_B ? STAGE_B : RED_B;
  __shared__ __align__(16) char smem[SMEM_B];
  u16* as = (u16*)smem;                       // [KW][2][ASZ]
  u16* bs = as + KW * 2 * ASZ;                // [KW][2][BSZ]

  int isf = 0;
  if (MODE == 2 || MODE == 3) isf = *flagp;
  const int Lb = blockIdx.x;
  const int xcd = Lb & 7, sidx = Lb >> 3;
  const int SH = 1 << SHL;
  const int by = xcd * SH + (sidx & (SH - 1));
  const int bx = sidx >> SHL;
  const int tid = threadIdx.x;
  const int L = tid & 63, w = tid >> 6;
  const int g = w >> 2, wl = w & 3;    // wave-group (K-split), wave-in-group
  const int wm = (wl >> 1) * (TM >> 1), wn = (wl & 1) << 6;
  const int row0 = by * TM, col0 = bx << 7;
  const int m = L & 15, quad = L >> 4;

  f32x4 zero4 = {0.f, 0.f, 0.f, 0.f};
  f32x4 acc[WR][4];
#pragma unroll
  for (int i = 0; i < WR; i++)
#pragma unroll
    for (int j = 0; j < 4; j++) acc[i][j] = zero4;

  const int KSEG = K / KW;
  const int aoff = (wm + m) * 32 + quad * 8;
  const int boff = (wn + m) * 32 + quad * 8;
  const int rA = L >> 2, c8 = (L & 3) << 3;   // lane's row-in-chunk / col
  constexpr int NA = TM / 64;                 // A chunks per wave (1 or 2)

  // issue async staging of K-step kk into buffer buf
  auto stage = [&](int buf, int kk) {
    u16* asgb = as + ((g << 1) + buf) * ASZ;
    u16* bsgb = bs + ((g << 1) + buf) * BSZ;
#pragma unroll
    for (int c = 0; c < NA; c++) {
      const u16* gp = A + (size_t)(row0 + wl * 16 * NA + c * 16 + rA) * K
                        + g * KSEG + kk + c8;
      load_lds16(gp, asgb + (wl * NA + c) * 512);
    }
#pragma unroll
    for (int c = 0; c < 2; c++) {
      const u16* gp = BT + (size_t)(col0 + wl * 32 + c * 16 + rA) * K
                         + g * KSEG + kk + c8;
      load_lds16(gp, bsgb + (wl * 2 + c) * 512);
    }
  };

  // per-step LDS->frag + MFMA
  auto compute_step = [&](int buf) {
    const u16* asgb = as + ((g << 1) + buf) * ASZ;
    const u16* bsgb = bs + ((g << 1) + buf) * BSZ;
    bf16x8 af[WR], bfr[4];
#pragma unroll
    for (int i = 0; i < WR; i++) af[i]  = *(const bf16x8*)&asgb[aoff + i * 512];
#pragma unroll
    for (int j = 0; j < 4; j++) bfr[j] = *(const bf16x8*)&bsgb[boff + j * 512];
#pragma unroll
    for (int i = 0; i < WR; i++)
#pragma unroll
      for (int j = 0; j < 4; j++)
        acc[i][j] = __builtin_amdgcn_mfma_f32_16x16x32_bf16(af[i], bfr[j], acc[i][j], 0, 0, 0);
  };

  const int nt = KSEG / 32;
  stage(0, 0);
  __syncthreads();                       // drain prologue staging
  int buf = 0;
  for (int t = 0; t < nt; ++t) {
    if (t + 1 < nt) stage(buf ^ 1, (t + 1) * 32);   // async, in flight
    compute_step(buf);
    __syncthreads();                     // publish staged tile + retire readers
    buf ^= 1;
  }

  if (KW > 1) {
    // combine group 1's accumulators into group 0 through padded LDS.
    float* red = (float*)smem;
    if (g == 1) {
#pragma unroll
      for (int i = 0; i < WR; i++)
#pragma unroll
        for (int j = 0; j < 4; j++)
#pragma unroll
          for (int r = 0; r < 4; r++)
            red[(wm + i * 16 + quad * 4 + r) * 132 + wn + j * 16 + m] = acc[i][j][r];
    }
    __syncthreads();
    if (g == 0) {
#pragma unroll
      for (int i = 0; i < WR; i++)
#pragma unroll
        for (int j = 0; j < 4; j++)
#pragma unroll
          for (int r = 0; r < 4; r++)
            acc[i][j][r] += red[(wm + i * 16 + quad * 4 + r) * 132 + wn + j * 16 + m];
    }
  }

  if (g == 0) {
#pragma unroll
    for (int j = 0; j < 4; j++) {
      const int col = col0 + wn + j * 16 + m;
      const float bval = bias[col];
      if (MODE == 4) {
        const int sel = col >> 10;
        const int hh  = (col >> 6) & 15;
        const int f   = col & 63;
#pragma unroll
        for (int i = 0; i < WR; i++) {
          const int rowb = row0 + wm + i * 16 + quad * 4;
          if (sel < 2) {
            u16* dst = (u16*)(sel ? out2 : out);
#pragma unroll
            for (int r = 0; r < 4; r++)
              dst[((((size_t)hh << 12) + rowb + r) << 6) + f] = f2bf(acc[i][j][r] + bval);
          } else {
            uint2 o;
            o.x = pkbf(acc[i][j][0] + bval, acc[i][j][1] + bval);
            o.y = pkbf(acc[i][j][2] + bval, acc[i][j][3] + bval);
            *(uint2*)&((u16*)out3)[(((size_t)hh * 64 + f) << 12) + rowb] = o;
          }
        }
      } else {
#pragma unroll
        for (int i = 0; i < WR; i++) {
          const int rowb = row0 + wm + i * 16 + quad * 4;
#pragma unroll
          for (int r = 0; r < 4; r++) {
            float vv = acc[i][j][r] + bval;
            size_t idx = (size_t)(rowb + r) * N + col;
            if (MODE == 1) {
              ((u16*)out)[idx] = f2bf(fmaxf(vv, 0.f));
            } else if (MODE == 2) {
              ((float*)out)[idx] = vv + loadf(resid, idx, isf);
            } else if (MODE == 3) {
              float o = vv + ((const float*)resid)[idx];
              if (isf) ((float*)out)[idx] = o;
              else     ((u16*)out)[idx]   = f2bf(o);
            }
          }
        }
      }
    }
  }
}

// ---------------------------------------------------------------------------
// Flash attention, split-K, hybrid-MFMA transposed form.
// R14: 128-q tiles, launch_bounds(512,4) -> 128-reg cap, zero spill.
// R20 (T14): DOUBLE-BUFFERED K/V LDS, ONE barrier per step. Next-step
// global loads issued BEFORE compute (kr/vr live across the phase),
// ds_write to buf^1 AFTER compute, single barrier publishes. Load latency
// hides under QK/softmax/PV. Layouts (pad/permute) unchanged.
// ---------------------------------------------------------------------------
__global__ __launch_bounds__(512, 4) void attn_part(
    const u16* __restrict__ qh, const u16* __restrict__ kh,
    const u16* __restrict__ vT, u16* __restrict__ Opart,
    float* __restrict__ stats, u16* __restrict__ z) {
  const int combo = blockIdx.x;      // h*2 + b
  const int qt = blockIdx.y;         // 0..15 (128-row q-tiles)
  const int ci = blockIdx.z;         // 0..1 (1024-chunks)
  const int q0 = qt << 7;
  const int nc = (q0 + 128 + 1023) >> 10;
  if (ci >= nc) return;
  const int k_lo = ci << 10;
  const int k_hi = min(k_lo + 1024, q0 + 128);
  const int nsteps = (k_hi - k_lo + 127) >> 7;

  __shared__ u16 kS[2][128 * 72];    // K tiles [buf][tok][64+8 pad]; [0] reused as O bounce
  __shared__ u16 vS[2][64 * 136];    // V^T tiles [buf][f][128 permuted + 8 pad]
  const int tid = threadIdx.x, L = tid & 63, w = tid >> 6;   // w 0..7
  const int m = L & 15, quad = L >> 4;
  const int h = combo >> 1, b = combo & 1;
  const size_t tb = (size_t)b * 2048;
  const size_t hbase = (size_t)h * 4096;
  const int qg = q0 + w * 16 + m;    // this lane's global q (column)

  // Q as 16x16x32 B-frags: lane n=q, k=feat quad*8+j (two 32-feat chunks)
  bf16x8 qb0, qb1;
  {
    const u16* qp = qh + ((hbase + tb + (size_t)qg) << 6) + quad * 8;
    qb0 = *(const bf16x8*)qp;
    qb1 = *(const bf16x8*)(qp + 32);
  }

  f32x4 zero4 = {0.f, 0.f, 0.f, 0.f};
  f32x4 O[4];                        // O^T: lane q, f = ft*16 + quad*4 + r
#pragma unroll
  for (int ft = 0; ft < 4; ft++) O[ft] = zero4;
  float mrow = -30000.f, lrow = 0.f;

  // staging: 512 thr, K tile 128x64 (1024 int4, 2 per thread),
  // V tile 64x128 (1024 int4, 2 per thread)
  const int krow[2] = { (0*512+tid) >> 3, (1*512+tid) >> 3 };
  const int kc = tid & 7;
  const int vf[2] = { (0*512+tid) >> 4, (1*512+tid) >> 4 };
  const int vc = tid & 15;
  // permuted V column bases for the two 4-elem halves of each int4
  const int vq = (vc & 1) << 1;             // quad base 2*(vc&1)
  const int vk4 = (vc >> 1) << 2;           // kt*4
  const int vc0 = (vq << 5) + vk4;          // quad*32 + kt*4
  const int vc1 = ((vq + 1) << 5) + vk4;

  // prologue: load + stage step 0 into buf 0, one barrier
  int4 kr[2], vr[2];
#pragma unroll
  for (int i = 0; i < 2; i++) {
    kr[i] = *(const int4*)(kh + ((hbase + tb + k_lo + krow[i]) << 6) + kc * 8);
    vr[i] = *(const int4*)(vT + (((size_t)h * 64 + vf[i]) << 12) + tb + k_lo + vc * 8);
  }
#pragma unroll
  for (int i = 0; i < 2; i++) {
    *(int4*)&kS[0][krow[i] * 72 + kc * 8] = kr[i];
    union { int4 v; s16x4 hh[2]; } tv; tv.v = vr[i];
    *(s16x4*)&vS[0][vf[i] * 136 + vc0] = tv.hh[0];
    *(s16x4*)&vS[0][vf[i] * 136 + vc1] = tv.hh[1];
  }
  __syncthreads();

  for (int j = 0; j < nsteps; j++) {
    const int cur = j & 1;
    const bool pf = (j + 1 < nsteps);
    const int k0 = k_lo + (j << 7);
    // T14 issue-early: next step's loads start now, land after compute
    if (pf) {
      const int k1 = k_lo + ((j + 1) << 7);
#pragma unroll
      for (int i = 0; i < 2; i++) {
        kr[i] = *(const int4*)(kh + ((hbase + tb + k1 + krow[i]) << 6) + kc * 8);
        vr[i] = *(const int4*)(vT + (((size_t)h * 64 + vf[i]) << 12) + tb + k1 + vc * 8);
      }
    }

    // two 64-token halves: sc[4] live instead of sc[8]
#pragma unroll
    for (int hs = 0; hs < 2; hs++) {
      const int kbase = k0 + hs * 64;
      f32x4 sc[4];
#pragma unroll
      for (int kt4 = 0; kt4 < 4; kt4++) {
        const int kt = hs * 4 + kt4;
        const u16* kp = &kS[cur][(kt * 16 + m) * 72 + quad * 8];
        bf16x8 ka0 = *(const bf16x8*)kp;
        bf16x8 ka1 = *(const bf16x8*)(kp + 32);
        f32x4 t = zero4;
        t = __builtin_amdgcn_mfma_f32_16x16x32_bf16(ka0, qb0, t, 0, 0, 0);
        t = __builtin_amdgcn_mfma_f32_16x16x32_bf16(ka1, qb1, t, 0, 0, 0);
        sc[kt4] = t;
      }
      if (kbase + 64 > q0) {   // touches diagonal region: causal mask
#pragma unroll
        for (int kt4 = 0; kt4 < 4; kt4++)
#pragma unroll
          for (int r = 0; r < 4; r++) {
            int ktok = kbase + kt4 * 16 + quad * 4 + r;
            if (ktok > qg) sc[kt4][r] = -30000.f;
          }
      }
      // per-lane max over 16 regs + 2 shuffles (q fixed per lane)
      float mx = sc[0][0];
#pragma unroll
      for (int kt4 = 0; kt4 < 4; kt4++)
#pragma unroll
        for (int r = 0; r < 4; r++) mx = fmaxf(mx, sc[kt4][r]);
      mx = fmaxf(mx, __shfl_xor(mx, 16, 64));
      mx = fmaxf(mx, __shfl_xor(mx, 32, 64));
      // defer-max (T13): only rescale when max grew by > 8 (exp2 domain)
      if (!__all(mx <= mrow + 8.f)) {
        float mnew = fmaxf(mrow, mx);
        float alpha = __builtin_amdgcn_exp2f(mrow - mnew);
        lrow *= alpha;
#pragma unroll
        for (int ft = 0; ft < 4; ft++) O[ft] *= alpha;
        mrow = mnew;
      }
      // P^T = exp2(S^T - m): pack to bf16 B-frags; accumulate l inline
      s16x4 pb[4];
      float sum = 0.f;
#pragma unroll
      for (int kt4 = 0; kt4 < 4; kt4++) {
        float e0 = __builtin_amdgcn_exp2f(sc[kt4][0] - mrow);
        float e1 = __builtin_amdgcn_exp2f(sc[kt4][1] - mrow);
        float e2 = __builtin_amdgcn_exp2f(sc[kt4][2] - mrow);
        float e3 = __builtin_amdgcn_exp2f(sc[kt4][3] - mrow);
        sum += (e0 + e1) + (e2 + e3);
        union { uint2 u; s16x4 hh; } pu;
        pu.u.x = pkbf(e0, e1);
        pu.u.y = pkbf(e2, e3);
        pb[kt4] = pu.hh;
      }
      sum += __shfl_xor(sum, 16, 64);
      sum += __shfl_xor(sum, 32, 64);
      lrow += sum;
      // O^T += V^T·P^T via 16x16x16 over this half's k-slots
#pragma unroll
      for (int ft = 0; ft < 4; ft++) {
        const u16* vp = &vS[cur][(ft * 16 + m) * 136 + quad * 32 + hs * 16];
#pragma unroll
        for (int p2 = 0; p2 < 2; p2++) {
          union { bf16x8 v; s16x4 hh[2]; } u;
          u.v = *(const bf16x8*)(vp + p2 * 8);
          O[ft] = mfma16(u.hh[0], pb[2 * p2],     O[ft]);
          O[ft] = mfma16(u.hh[1], pb[2 * p2 + 1], O[ft]);
        }
      }
    }

    // T14 write-late: stage next step into the other buffer; our reads of
    // buf cur are done, other waves only READ cur -> no conflict. One
    // barrier publishes writes (and orders next iteration's reads).
    if (pf) {
      const int nb2 = cur ^ 1;
#pragma unroll
      for (int i = 0; i < 2; i++) {
        *(int4*)&kS[nb2][krow[i] * 72 + kc * 8] = kr[i];
        union { int4 v; s16x4 hh[2]; } tv; tv.v = vr[i];
        *(s16x4*)&vS[nb2][vf[i] * 136 + vc0] = tv.hh[0];
        *(s16x4*)&vS[nb2][vf[i] * 136 + vc1] = tv.hh[1];
      }
    }
    __syncthreads();
  }

  // nc==1: normalize in-kernel (diagonal guarantees lrow > 0)
  if (nc == 1) {
    float inv = 1.f / lrow;
#pragma unroll
    for (int ft = 0; ft < 4; ft++) O[ft] *= inv;
  }

  // O^T -> LDS bounce (kS[0] reused, 128 rows x 64f) -> coalesced stores
  // (loop-end barrier already separates last compute from this write)
#pragma unroll
  for (int ft = 0; ft < 4; ft++) {
    union { uint2 u; s16x4 hh; } o4;
    o4.u.x = pkbf(O[ft][0], O[ft][1]);
    o4.u.y = pkbf(O[ft][2], O[ft][3]);
    *(s16x4*)&kS[0][(w * 16 + m) * 72 + ft * 16 + quad * 4] = o4.hh;
  }
  __syncthreads();
  if (nc == 1) {
    // direct z write: [tok][1024] layout, this head's 64-col stripe
    u16* zp = z + ((tb + (size_t)q0) << 10) + h * 64;
#pragma unroll
    for (int it = 0; it < 2; it++) {
      int idx = it * 512 + tid;
      int row = idx >> 3, c = idx & 7;
      *(int4*)&zp[((size_t)row << 10) + c * 8] = *(const int4*)&kS[0][row * 72 + c * 8];
    }
  } else {
    const int slot = (combo * 16 + qt) * 2 + ci;
    u16* op = Opart + ((size_t)slot << 13);
#pragma unroll
    for (int it = 0; it < 2; it++) {
      int idx = it * 512 + tid;
      int row = idx >> 3, c = idx & 7;
      *(int4*)&op[row * 64 + c * 8] = *(const int4*)&kS[0][row * 72 + c * 8];
    }
    if (quad == 0) {
      stats[slot * 256 + w * 16 + m]       = mrow;
      stats[slot * 256 + 128 + w * 16 + m] = lrow;
    }
  }
}

// merge partials -> z [t][1024]; only qt>=8 tiles (nc==2) reach here. 512 thr.
__global__ __launch_bounds__(512) void attn_merge(
    const u16* __restrict__ Opart, const float* __restrict__ stats,
    u16* __restrict__ z) {
  const int combo = blockIdx.x, qt = 8 + blockIdx.y;
  const int h = combo >> 1, b = combo & 1;
  const int q0 = qt << 7;
  const int tid = threadIdx.x;
  const int t = tid >> 2, f0 = (tid & 3) << 4;   // t 0..127
  const int slot0 = (combo * 16 + qt) * 2;
  float M = fmaxf(stats[slot0 * 256 + t], stats[(slot0 + 1) * 256 + t]);
  float acc[16];
#pragma unroll
  for (int e = 0; e < 16; e++) acc[e] = 0.f;
  float ltot = 0.f;
#pragma unroll
  for (int ci = 0; ci < 2; ci++) {
    float mi = stats[(slot0 + ci) * 256 + t];
    float li = stats[(slot0 + ci) * 256 + 128 + t];
    float wgt = exp2f(mi - M);
    ltot += wgt * li;
    const u16* op = Opart + (((size_t)(slot0 + ci)) << 13) + t * 64 + f0;
    union { int4 v; u16 u[8]; } a0, a1;
    a0.v = *(const int4*)op;
    a1.v = *(const int4*)(op + 8);
#pragma unroll
    for (int e = 0; e < 8; e++) {
      acc[e]     += wgt * bf2f(a0.u[e]);
      acc[8 + e] += wgt * bf2f(a1.u[e]);
    }
  }
  float inv = 1.f / ltot;
  union { int4 v; u16 u[8]; } o0, o1;
#pragma unroll
  for (int e = 0; e < 8; e++) {
    o0.u[e] = f2bf(acc[e] * inv);
    o1.u[e] = f2bf(acc[8 + e] * inv);
  }
  size_t tok = (size_t)b * 2048 + q0 + t;
  *(int4*)&z[tok * 1024 + h * 64 + f0]     = o0.v;
  *(int4*)&z[tok * 1024 + h * 64 + f0 + 8] = o1.v;
}

// ---------------------------------------------------------------------------
extern "C" void kernel_launch(void* const* d_in, const int* in_sizes, int n_in,
                              void* d_out, int out_size, void* d_ws, size_t ws_size,
                              hipStream_t stream) {
  (void)in_sizes; (void)n_in; (void)out_size; (void)ws_size;
  const void* resid_pre = d_in[0];
  const void* ln1_w = d_in[1];
  const void* ln1_b = d_in[2];
  const void* W_Q   = d_in[3];
  const void* b_Q   = d_in[4];
  const void* W_K   = d_in[5];
  const void* b_K   = d_in[6];
  const void* W_V   = d_in[7];
  const void* b_V   = d_in[8];
  const void* W_O   = d_in[9];
  const void* b_O   = d_in[10];
  const void* ln2_w = d_in[11];
  const void* ln2_b = d_in[12];
  const void* W_in  = d_in[13];
  const void* b_in  = d_in[14];
  const void* W_out = d_in[15];
  const void* b_out = d_in[16];

  char* p = (char*)d_ws;
  auto alloc = [&](size_t bytes) {
    char* r = p; p += (bytes + 255) & ~(size_t)255; return (void*)r;
  };
  int*   flag      = (int*)  alloc(256);
  u16*   WqkvT     = (u16*)  alloc(3072ull * 1024 * 2);
  u16*   WoT       = (u16*)  alloc(1024ull * 1024 * 2);
  u16*   WinT      = (u16*)  alloc(4096ull * 1024 * 2);
  u16*   WoutT     = (u16*)  alloc(1024ull * 4096 * 2);
  float* biases    = (float*)alloc(9216 * 4);
  u16*   xn        = (u16*)  alloc(4096ull * 1024 * 2);  // reused as z
  u16*   q_hm      = (u16*)  alloc(16ull * 4096 * 64 * 2);
  u16*   k_hm      = (u16*)  alloc(16ull * 4096 * 64 * 2);
  u16*   vTws      = (u16*)  alloc(16ull * 64 * 4096 * 2);
  float* resid_mid = (float*)alloc(4096ull * 1024 * 4);
  u16*   h2        = (u16*)  alloc(4096ull * 1024 * 2);  // attn stats before ln2
  u16*   act       = (u16*)  alloc(4096ull * 4096 * 2);  // attn partials before MLP
  float* part3     = (float*)alloc(4096ull * 1024 * 4);  // split-K chunk 3
  u16*   z = xn;
  u16*   Opart = act;              // 1024 slots x 16 KB = 16 MB (< 32 MB)
  float* stats = (float*)h2;       // 1024 slots x 256 fp32 = 1 MB < 8 MB
  // R19 split-K partial buffers (each exactly 16 MB, DEAD by final gemm):
  //   part0 = WqkvT(6MB)+WoT(2MB)+WinT(8MB)  [contiguous, ends at WoutT]
  //   part1 = xn(8MB)+q_hm(8MB)
  //   part2 = k_hm(8MB)+vTws(8MB)            [ends exactly at resid_mid]
  //   part3 = fresh 16MB alloc
  float* part0 = (float*)WqkvT;
  float* part1 = (float*)xn;
  float* part2 = (float*)k_hm;

  detect_dtype<<<1, 256, 0, stream>>>((const unsigned int*)resid_pre, flag);

  pack_qkv_tiled<<<dim3(16, 48), 256, 0, stream>>>(flag, W_Q, W_K, W_V, WqkvT);
  transpose_tiled<<<dim3(16, 16), 256, 0, stream>>>(flag, W_O,   WoT,   1024, 1024);
  transpose_tiled<<<dim3(64, 16), 256, 0, stream>>>(flag, W_in,  WinT,  1024, 4096);
  transpose_tiled<<<dim3(16, 64), 256, 0, stream>>>(flag, W_out, WoutT, 4096, 1024);
  pack_biases<<<36, 256, 0, stream>>>(flag, b_Q, b_K, b_V, b_O, b_in, b_out, biases);

  ln_fwd<0><<<4096, 256, 0, stream>>>(flag, resid_pre, ln1_w, ln1_b, xn);
  // qkv -> head-major q/k + transposed v. grid: 8 XCD x SH=4 rows x 24 cols
  gemm_bt<4, 128, 1><<<768, 256, 0, stream>>>(
      flag, xn, WqkvT, biases, nullptr, q_hm, k_hm, vTws, 4096, 3072, 1024, 2);
  // split-K causal flash attention (128-q tiles, 1024-chunks) -> z
  attn_part<<<dim3(32, 16, 2), 512, 0, stream>>>(q_hm, k_hm, vTws, Opart, stats, z);
  attn_merge<<<dim3(32, 8), 512, 0, stream>>>(Opart, stats, z);
  // resid_mid = resid_pre + z @ W_O + b_O   (fp32). 8 XCD x SH=8 x 8 cols,
  // in-block split-K (512 thr), gload_lds dbuf staging
  gemm_bt<2, 64, 2><<<512, 512, 0, stream>>>(
      flag, z, WoT, biases + 3072, resid_pre, resid_mid, nullptr, nullptr, 4096, 1024, 1024, 3);
  ln_fwd<1><<<4096, 256, 0, stream>>>(flag, resid_mid, ln2_w, ln2_b, h2);
  // act = relu(h2 @ W_in + b_in). 256^2-tile 4-phase counted-vmcnt template.
  gemm256<0><<<256, 512, 0, stream>>>(h2, WinT, biases + 4096, act,
                                      nullptr, nullptr, nullptr, nullptr,
                                      4096, 4096, 1024);
  // out = resid_mid + act @ W_out + b_out. SPLIT-K=4 on the 256^2
  // template (256 blocks = 1/CU, nt=16) -> fp32 partials -> fused reduce.
  gemm256<1><<<256, 512, 0, stream>>>(act, WoutT, nullptr, nullptr,
                                      part0, part1, part2, part3,
                                      4096, 1024, 4096);
  reduce_sk<<<4096, 256, 0, stream>>>(flag, part0, part1, part2, part3,
                                      biases + 8192, resid_mid, d_out);
}

// Round 13
// 396.569 us; speedup vs baseline: 1.0188x; 1.0188x over previous
//
#include <hip/hip_runtime.h>
#include <stdint.h>

// ---------------------------------------------------------------------------
// TransformerBlock on MI355X (gfx950). Runtime dtype detection (fp32 vs bf16
// inputs), bf16-MFMA internal compute, fp32 accumulation + fp32 residual path.
// B=2 S=2048 D=1024 H=16 K=64 MLP=4096; tokens M = 4096.
// R14: attn spill fix (gfx950 UNIFIED VGPR/AGPR file; launch_bounds caps
// TOTAL regs) -> 414. R16: gload_lds+dbuf 2-phase gemms -> 410. R17/R18:
// MLP-up on 256^2 4-phase counted-vmcnt template (final-iter vmcnt race
// fixed) -> 405.4. R19: MLP-down split-K=4 on the same template + fused
// reduce (partials in dead ws buffers) -> 403.3.
// R20 (NEUTRAL, REVERTED): T14 dbuf+single-barrier on attn -> 404.0; with
// 16 waves/CU the JIT loads were already latency-covered (T14-null-at-
// high-TLP, m219/m238); occupancy capped at 2 blocks/CU by reg tiers.
// R21: attn_part restored to R19 structure + T5 s_setprio(1) around the
// QK and PV MFMA clusters (measured +4-7% attn, m191: independent
// co-resident blocks at different phases -> scheduler can favor the
// MFMA-entering wave while the other block runs softmax VALU).
// ---------------------------------------------------------------------------

typedef unsigned short u16;
typedef __bf16 bf16x8 __attribute__((ext_vector_type(8)));
typedef __bf16 bf16x4 __attribute__((ext_vector_type(4)));
typedef __bf16 bf16x2 __attribute__((ext_vector_type(2)));
typedef short  s16x4  __attribute__((ext_vector_type(4)));
typedef float  f32x4  __attribute__((ext_vector_type(4)));

#define QSCALE 0.18033688011112042f   // (1/sqrt(64)) * log2(e): softmax via exp2

__device__ __forceinline__ float bf2f(unsigned int u) {
  union { unsigned int u; float f; } v; v.u = u << 16; return v.f;
}
__device__ __forceinline__ u16 f2bf(float f) {
  union { float f; unsigned int u; } v; v.f = f;
  unsigned int r = v.u + 0x7FFFu + ((v.u >> 16) & 1u);   // RNE
  return (u16)(r >> 16);
}
__device__ __forceinline__ unsigned pkbf(float lo, float hi) {
#if __has_builtin(__builtin_amdgcn_cvt_pk_bf16_f32)
  bf16x2 t = __builtin_amdgcn_cvt_pk_bf16_f32(lo, hi);
  return __builtin_bit_cast(unsigned, t);
#else
  return (unsigned)f2bf(lo) | ((unsigned)f2bf(hi) << 16);
#endif
}
__device__ __forceinline__ float loadf(const void* p, size_t i, int isf) {
  return isf ? ((const float*)p)[i] : bf2f(((const u16*)p)[i]);
}

// async global->LDS, 16B per lane; LDS dest must be wave-uniform base
// (HW writes base + lane*16), global src is per-lane.
__device__ __forceinline__ void load_lds16(const u16* g, u16* l) {
  __builtin_amdgcn_global_load_lds(
      (const __attribute__((address_space(1))) void*)g,
      (__attribute__((address_space(3))) void*)l, 16, 0, 0);
}

// 16x16x16 bf16 MFMA wrapper
__device__ __forceinline__ f32x4 mfma16(s16x4 a, s16x4 b, f32x4 c) {
#if __has_builtin(__builtin_amdgcn_mfma_f32_16x16x16_bf16)
  return __builtin_amdgcn_mfma_f32_16x16x16_bf16(
      __builtin_bit_cast(bf16x4, a), __builtin_bit_cast(bf16x4, b), c, 0, 0, 0);
#else
  return __builtin_amdgcn_mfma_f32_16x16x16bf16_1k(a, b, c, 0, 0, 0);
#endif
}

// ---------------------------------------------------------------------------
__global__ __launch_bounds__(256) void detect_dtype(
    const unsigned int* __restrict__ x, int* __restrict__ flag) {
  __shared__ int cnt;
  if (threadIdx.x == 0) cnt = 0;
  __syncthreads();
  int c = 0;
  for (int i = threadIdx.x; i < 512; i += 256) {
    unsigned int e = (x[i] >> 23) & 0xFFu;
    if (e >= 97u && e <= 157u) c++;
  }
  atomicAdd(&cnt, c);
  __syncthreads();
  if (threadIdx.x == 0) *flag = (cnt > 384) ? 1 : 0;
}

// ---------------------------------------------------------------------------
// Tiled transposes: 64x64 tiles through LDS (stride-65 pad -> 2-way = free).
// ---------------------------------------------------------------------------
__global__ __launch_bounds__(256) void pack_qkv_tiled(
    const int* __restrict__ flagp,
    const void* __restrict__ Wq, const void* __restrict__ Wk, const void* __restrict__ Wv,
    u16* __restrict__ WT) {
  __shared__ float t[64][65];
  const int isf = *flagp;
  const int tid = threadIdx.x;
  const int mh = blockIdx.y;            // mat*16 + h
  const int mat = mh >> 4, h = mh & 15;
  const int d0 = blockIdx.x << 6;       // d-tile
  const void* src = (mat == 0) ? Wq : (mat == 1) ? Wk : Wv;
  const float scale = (mat == 0) ? QSCALE : 1.f;
  const int lane = tid & 63, rr = tid >> 6;
  const size_t sbase = ((size_t)h << 16) + lane;
#pragma unroll
  for (int i = 0; i < 16; i++) {
    int d = i * 4 + rr;
    t[d][lane] = loadf(src, sbase + (size_t)(d0 + d) * 64, isf) * scale;
  }
  __syncthreads();
#pragma unroll
  for (int i = 0; i < 16; i++) {
    int k = i * 4 + rr;
    WT[((size_t)((mat << 10) + (h << 6) + k) << 10) + d0 + lane] = f2bf(t[lane][k]);
  }
}

__global__ __launch_bounds__(256) void transpose_tiled(
    const int* __restrict__ flagp, const void* __restrict__ src,
    u16* __restrict__ dst, int R, int C) {
  __shared__ float t[64][65];
  const int isf = *flagp;
  const int tid = threadIdx.x;
  const int c0 = blockIdx.x << 6, r0 = blockIdx.y << 6;
  const int lane = tid & 63, rr = tid >> 6;
#pragma unroll
  for (int i = 0; i < 16; i++) {
    int r = i * 4 + rr;
    t[r][lane] = loadf(src, (size_t)(r0 + r) * C + c0 + lane, isf);
  }
  __syncthreads();
#pragma unroll
  for (int i = 0; i < 16; i++) {
    int c = i * 4 + rr;
    dst[(size_t)(c0 + c) * R + r0 + lane] = f2bf(t[lane][c]);
  }
}

__global__ __launch_bounds__(256) void pack_biases(
    const int* __restrict__ flagp,
    const void* bq, const void* bk, const void* bv,
    const void* bO, const void* bin, const void* bout,
    float* __restrict__ out) {
  const int isf = *flagp;
  int i = blockIdx.x * 256 + threadIdx.x;
  float v;
  if (i < 1024)      v = loadf(bq,   i,        isf) * QSCALE;
  else if (i < 2048) v = loadf(bk,   i - 1024, isf);
  else if (i < 3072) v = loadf(bv,   i - 2048, isf);
  else if (i < 4096) v = loadf(bO,   i - 3072, isf);
  else if (i < 8192) v = loadf(bin,  i - 4096, isf);
  else               v = loadf(bout, i - 8192, isf);
  out[i] = v;
}

// ---------------------------------------------------------------------------
template<int SRC>
__global__ __launch_bounds__(256) void ln_fwd(
    const int* __restrict__ flagp, const void* __restrict__ xin,
    const void* __restrict__ w, const void* __restrict__ b,
    u16* __restrict__ out) {
  const int isf = *flagp;
  const int row = blockIdx.x, tid = threadIdx.x;
  const int col = tid << 2;
  const size_t base = ((size_t)row << 10) + col;
  float v[4];
#pragma unroll
  for (int i = 0; i < 4; i++)
    v[i] = (SRC == 1) ? ((const float*)xin)[base + i] : loadf(xin, base + i, isf);
  float s  = v[0] + v[1] + v[2] + v[3];
  float ss = v[0]*v[0] + v[1]*v[1] + v[2]*v[2] + v[3]*v[3];
#pragma unroll
  for (int mk = 32; mk >= 1; mk >>= 1) {
    s  += __shfl_xor(s,  mk, 64);
    ss += __shfl_xor(ss, mk, 64);
  }
  __shared__ float red[8];
  if ((tid & 63) == 0) { red[tid >> 6] = s; red[4 + (tid >> 6)] = ss; }
  __syncthreads();
  float S  = red[0] + red[1] + red[2] + red[3];
  float SS = red[4] + red[5] + red[6] + red[7];
  float mean = S * (1.f / 1024.f);
  float var  = SS * (1.f / 1024.f) - mean * mean;
  float rstd = rsqrtf(var + 1e-5f);
  u16 e[4];
#pragma unroll
  for (int i = 0; i < 4; i++) {
    float wv = loadf(w, col + i, isf);
    float bv = loadf(b, col + i, isf);
    e[i] = f2bf((v[i] - mean) * rstd * wv + bv);
  }
  uint2 o;
  o.x = (unsigned)e[0] | ((unsigned)e[1] << 16);
  o.y = (unsigned)e[2] | ((unsigned)e[3] << 16);
  *(uint2*)(out + base) = o;
}

// ---------------------------------------------------------------------------
// R17/R18/R19: 256x256-tile 4-phase GEMM with counted vmcnt (m201 template).
// EPI=0: C = relu(A @ BT^T + bias) -> bf16, full K, grid (M/256)x(N/256)
//        XCD-striped (256 blocks @ MODE 1).
// EPI=1: fp32 partials, SPLIT-K/4: grid 16row x 4col x 4kc = 256 blocks;
//        block computes its 256x256 tile over K-chunk kc, stores raw acc
//        to pp[row*N+col] (pp selected from p0..p3 by kc). nt = K/256.
// 512 thr / 8 waves (2Mx4N); per-wave output 128x64 (acc[8][4] f32x4).
// LDS 128KB: [2 buf][4 unit][8192 u16]; unit = 256 rows x 32 k (A or BT).
// Swizzle: 16B chunk ^= (row>>1)&3, write via pre-swizzled global src,
// read via XOR on ds_read addr (both-sides involution).
// vmcnt ledger (verified R18): steady end-ph0 vmcnt(2) (final: vmcnt(0));
// end-ph3 vmcnt(4).
// ---------------------------------------------------------------------------
template<int EPI>
__global__ __launch_bounds__(512, 2) void gemm256(
    const u16* __restrict__ A, const u16* __restrict__ BT,
    const float* __restrict__ bias, u16* __restrict__ out,
    float* __restrict__ p0, float* __restrict__ p1,
    float* __restrict__ p2, float* __restrict__ p3,
    int M, int N, int K) {
  __shared__ __align__(16) u16 lds[65536];   // 128 KB
  const int tid = threadIdx.x, L = tid & 63, w = tid >> 6;
  const int m = L & 15, quad = L >> 4;
  const int bid = blockIdx.x;
  int by, bx, kstart, nt;
  float* pp = nullptr;
  if constexpr (EPI == 0) {
    const int xcd = bid & 7, s = bid >> 3;
    const int spx = (M >> 8) >> 3;          // row-tiles per XCD
    by = xcd * spx + (s % spx);
    bx = s / spx;
    kstart = 0; nt = K >> 6;
  } else {
    const int xcd = bid & 7, s = bid >> 3;  // 256 blocks: 2row x 4col x 4kc per XCD
    by = xcd * 2 + (s & 1);
    const int r2 = s >> 1;
    bx = r2 & 3;
    const int kc = r2 >> 2;
    kstart = kc * (K >> 2);
    nt = K >> 8;                            // (K/4)/64
    pp = kc == 0 ? p0 : kc == 1 ? p1 : kc == 2 ? p2 : p3;
  }
  const int row0 = by << 8, col0 = bx << 8;
  const int wrow = (w >> 2) << 7, wcol = (w & 3) << 6;

  f32x4 acc[8][4];
#pragma unroll
  for (int i = 0; i < 8; i++)
#pragma unroll
    for (int j = 0; j < 4; j++) acc[i][j] = f32x4{0.f, 0.f, 0.f, 0.f};

  // staging constants: lane covers (row = w*16 + L>>2 [+128], chunk L&3)
  const int srow = (w << 4) + (L >> 2);
  const int lc   = (L & 3) ^ ((srow >> 1) & 3);   // (+128 preserves (row>>1)&3)
  const int ldst = w << 9;                         // elems within half (w*512)

  // stage one 16KB unit (2 x gload_lds per thread) of tile at kcol0
  auto stageU = [&](const u16* __restrict__ src, int srcRow0, int kcol0,
                    int nb, int u) {
#pragma unroll
    for (int half = 0; half < 2; half++) {
      const u16* g = src + (size_t)(srcRow0 + srow + half * 128) * K + kcol0 + lc * 8;
      load_lds16(g, &lds[(nb << 15) + (u << 13) + (half << 12) + ldst]);
    }
  };
  // A-frags: 4 row-frags for row-half rh from k-half kh of buffer b
  auto rdA = [&](int b, int kh, int rh, bf16x8* af) {
#pragma unroll
    for (int i = 0; i < 4; i++) {
      int row = wrow + rh * 64 + i * 16 + m;
      int off = (b << 15) + ((kh << 1) << 13) + row * 32
              + ((quad * 8) ^ (((row >> 1) & 3) << 3));
      af[i] = *(const bf16x8*)&lds[off];
    }
  };
  auto rdB = [&](int b, int kh, bf16x8* bf) {
#pragma unroll
    for (int j = 0; j < 4; j++) {
      int row = wcol + j * 16 + m;
      int off = (b << 15) + (((kh << 1) | 1) << 13) + row * 32
              + ((quad * 8) ^ (((row >> 1) & 3) << 3));
      bf[j] = *(const bf16x8*)&lds[off];
    }
  };

  // prologue: tile 0 -> buf 0 (units p0..p3); retire p0,p1; leave p2,p3 in flight
  stageU(A,  row0, kstart,      0, 0);
  stageU(BT, col0, kstart,      0, 1);
  stageU(A,  row0, kstart + 32, 0, 2);
  stageU(BT, col0, kstart + 32, 0, 3);
  asm volatile("s_waitcnt vmcnt(4)" ::: "memory");
  __builtin_amdgcn_s_barrier();

  for (int t = 0; t < nt; ++t) {
    const int b = t & 1, nb = b ^ 1;
    const bool pf = (t + 1 < nt);
    const int k1c = kstart + ((t + 1) << 6);
    bf16x8 af[4], bf0[4], bf1[4];
    // ---- phase 0: k-half 0, rows 0-63; stage A-k0(t+1) ----
    rdA(b, 0, 0, af); rdB(b, 0, bf0);
    if (pf) stageU(A, row0, k1c, nb, 0);
    __builtin_amdgcn_s_setprio(1);
#pragma unroll
    for (int i = 0; i < 4; i++)
#pragma unroll
      for (int j = 0; j < 4; j++)
        acc[i][j] = __builtin_amdgcn_mfma_f32_16x16x32_bf16(af[i], bf0[j], acc[i][j], 0, 0, 0);
    __builtin_amdgcn_s_setprio(0);
    // R18 fix: steady vmcnt(2) retires t p2,p3 (keeps t+1 p0 in flight);
    // FINAL iter (no stage issued) must drain to 0 else B-k1 races phase 1.
    if (pf) { asm volatile("s_waitcnt vmcnt(2)" ::: "memory"); }
    else    { asm volatile("s_waitcnt vmcnt(0)" ::: "memory"); }
    __builtin_amdgcn_s_barrier();
    // ---- phase 1: k-half 1, rows 0-63; stage B-k0(t+1) ----
    rdA(b, 1, 0, af); rdB(b, 1, bf1);
    if (pf) stageU(BT, col0, k1c, nb, 1);
    __builtin_amdgcn_s_setprio(1);
#pragma unroll
    for (int i = 0; i < 4; i++)
#pragma unroll
      for (int j = 0; j < 4; j++)
        acc[i][j] = __builtin_amdgcn_mfma_f32_16x16x32_bf16(af[i], bf1[j], acc[i][j], 0, 0, 0);
    __builtin_amdgcn_s_setprio(0);
    __builtin_amdgcn_s_barrier();
    // ---- phase 2: k-half 0, rows 64-127 (bf0 reused); stage A-k1(t+1) ----
    rdA(b, 0, 1, af);
    if (pf) stageU(A, row0, k1c + 32, nb, 2);
    __builtin_amdgcn_s_setprio(1);
#pragma unroll
    for (int i = 0; i < 4; i++)
#pragma unroll
      for (int j = 0; j < 4; j++)
        acc[4 + i][j] = __builtin_amdgcn_mfma_f32_16x16x32_bf16(af[i], bf0[j], acc[4 + i][j], 0, 0, 0);
    __builtin_amdgcn_s_setprio(0);
    __builtin_amdgcn_s_barrier();
    // ---- phase 3: k-half 1, rows 64-127 (bf1 reused); stage B-k1(t+1) ----
    rdA(b, 1, 1, af);
    if (pf) stageU(BT, col0, k1c + 32, nb, 3);
    __builtin_amdgcn_s_setprio(1);
#pragma unroll
    for (int i = 0; i < 4; i++)
#pragma unroll
      for (int j = 0; j < 4; j++)
        acc[4 + i][j] = __builtin_amdgcn_mfma_f32_16x16x32_bf16(af[i], bf1[j], acc[4 + i][j], 0, 0, 0);
    __builtin_amdgcn_s_setprio(0);
    asm volatile("s_waitcnt vmcnt(4)" ::: "memory");   // retire t+1 p0,p1 (final: trivial)
    __builtin_amdgcn_s_barrier();
  }

  if constexpr (EPI == 0) {
    // epilogue: relu + bias -> bf16
#pragma unroll
    for (int j = 0; j < 4; j++) {
      const int col = col0 + wcol + j * 16 + m;
      const float bval = bias[col];
#pragma unroll
      for (int i = 0; i < 8; i++) {
        const int rowb = row0 + wrow + i * 16 + quad * 4;
#pragma unroll
        for (int r = 0; r < 4; r++)
          out[(size_t)(rowb + r) * N + col] = f2bf(fmaxf(acc[i][j][r] + bval, 0.f));
      }
    }
  } else {
    // epilogue: raw fp32 partials (bias/resid applied in reduce_sk)
#pragma unroll
    for (int j = 0; j < 4; j++) {
      const int col = col0 + wcol + j * 16 + m;
#pragma unroll
      for (int i = 0; i < 8; i++) {
        const int rowb = row0 + wrow + i * 16 + quad * 4;
#pragma unroll
        for (int r = 0; r < 4; r++)
          pp[(size_t)(rowb + r) * N + col] = acc[i][j][r];
      }
    }
  }
}

// ---------------------------------------------------------------------------
// R19: reduce split-K partials: out = resid + p0+p1+p2+p3 + bias, flagged
// dtype. 4 fp32 elems/thread, fully coalesced int4 loads.
// ---------------------------------------------------------------------------
__global__ __launch_bounds__(256) void reduce_sk(
    const int* __restrict__ flagp,
    const float* __restrict__ p0, const float* __restrict__ p1,
    const float* __restrict__ p2, const float* __restrict__ p3,
    const float* __restrict__ bias, const float* __restrict__ resid,
    void* __restrict__ out) {
  const int isf = *flagp;
  const size_t base = ((size_t)blockIdx.x * 256 + threadIdx.x) * 4;
  const int col = (int)(base & 1023);
  f32x4 a0 = *(const f32x4*)(p0 + base);
  f32x4 a1 = *(const f32x4*)(p1 + base);
  f32x4 a2 = *(const f32x4*)(p2 + base);
  f32x4 a3 = *(const f32x4*)(p3 + base);
  f32x4 rs = *(const f32x4*)(resid + base);
  f32x4 o;
#pragma unroll
  for (int i = 0; i < 4; i++)
    o[i] = (a0[i] + a1[i]) + (a2[i] + a3[i]) + bias[col + i] + rs[i];
  if (isf) {
    *(f32x4*)((float*)out + base) = o;
  } else {
    uint2 pk;
    pk.x = pkbf(o[0], o[1]);
    pk.y = pkbf(o[2], o[3]);
    *(uint2*)((u16*)out + base) = pk;
  }
}

// ---------------------------------------------------------------------------
// GEMM C[M,N] = A[M,K] @ BT[N,K]^T + bias. KW*256 threads. (R16 structure,
// used for MODES 2/4.) gload_lds + double-buffered LDS, one barrier/step.
// ---------------------------------------------------------------------------
template<int MODE, int TM, int KW>
__global__ __launch_bounds__(KW * 256) void gemm_bt(
    const int* __restrict__ flagp,
    const u16* __restrict__ A, const u16* __restrict__ BT,
    const float* __restrict__ bias, const void* __restrict__ resid,
    void* __restrict__ out, void* __restrict__ out2, void* __restrict__ out3,
    int M, int N, int K, int SHL) {
  constexpr int WR = TM / 32;          // row-frags per wave
  constexpr int ASZ = TM * 32;         // per-group-per-buffer LDS elems (u16)
  constexpr int BSZ = 128 * 32;
  constexpr int STAGE_B = KW * 2 * (ASZ + BSZ) * 2;    // dbuf, bytes
  constexpr int RED_B = (KW > 1) ? TM * 132 * 4 : 1;   // padded fp32 combine
  constexpr int SMEM_B = STAGE_B > RED_B ? STAGE_B : RED_B;
  __shared__ __align__(16) char smem[SMEM_B];
  u16* as = (u16*)smem;                       // [KW][2][ASZ]
  u16* bs = as + KW * 2 * ASZ;                // [KW][2][BSZ]

  int isf = 0;
  if (MODE == 2 || MODE == 3) isf = *flagp;
  const int Lb = blockIdx.x;
  const int xcd = Lb & 7, sidx = Lb >> 3;
  const int SH = 1 << SHL;
  const int by = xcd * SH + (sidx & (SH - 1));
  const int bx = sidx >> SHL;
  const int tid = threadIdx.x;
  const int L = tid & 63, w = tid >> 6;
  const int g = w >> 2, wl = w & 3;    // wave-group (K-split), wave-in-group
  const int wm = (wl >> 1) * (TM >> 1), wn = (wl & 1) << 6;
  const int row0 = by * TM, col0 = bx << 7;
  const int m = L & 15, quad = L >> 4;

  f32x4 zero4 = {0.f, 0.f, 0.f, 0.f};
  f32x4 acc[WR][4];
#pragma unroll
  for (int i = 0; i < WR; i++)
#pragma unroll
    for (int j = 0; j < 4; j++) acc[i][j] = zero4;

  const int KSEG = K / KW;
  const int aoff = (wm + m) * 32 + quad * 8;
  const int boff = (wn + m) * 32 + quad * 8;
  const int rA = L >> 2, c8 = (L & 3) << 3;   // lane's row-in-chunk / col
  constexpr int NA = TM / 64;                 // A chunks per wave (1 or 2)

  // issue async staging of K-step kk into buffer buf
  auto stage = [&](int buf, int kk) {
    u16* asgb = as + ((g << 1) + buf) * ASZ;
    u16* bsgb = bs + ((g << 1) + buf) * BSZ;
#pragma unroll
    for (int c = 0; c < NA; c++) {
      const u16* gp = A + (size_t)(row0 + wl * 16 * NA + c * 16 + rA) * K
                        + g * KSEG + kk + c8;
      load_lds16(gp, asgb + (wl * NA + c) * 512);
    }
#pragma unroll
    for (int c = 0; c < 2; c++) {
      const u16* gp = BT + (size_t)(col0 + wl * 32 + c * 16 + rA) * K
                         + g * KSEG + kk + c8;
      load_lds16(gp, bsgb + (wl * 2 + c) * 512);
    }
  };

  // per-step LDS->frag + MFMA
  auto compute_step = [&](int buf) {
    const u16* asgb = as + ((g << 1) + buf) * ASZ;
    const u16* bsgb = bs + ((g << 1) + buf) * BSZ;
    bf16x8 af[WR], bfr[4];
#pragma unroll
    for (int i = 0; i < WR; i++) af[i]  = *(const bf16x8*)&asgb[aoff + i * 512];
#pragma unroll
    for (int j = 0; j < 4; j++) bfr[j] = *(const bf16x8*)&bsgb[boff + j * 512];
#pragma unroll
    for (int i = 0; i < WR; i++)
#pragma unroll
      for (int j = 0; j < 4; j++)
        acc[i][j] = __builtin_amdgcn_mfma_f32_16x16x32_bf16(af[i], bfr[j], acc[i][j], 0, 0, 0);
  };

  const int nt = KSEG / 32;
  stage(0, 0);
  __syncthreads();                       // drain prologue staging
  int buf = 0;
  for (int t = 0; t < nt; ++t) {
    if (t + 1 < nt) stage(buf ^ 1, (t + 1) * 32);   // async, in flight
    compute_step(buf);
    __syncthreads();                     // publish staged tile + retire readers
    buf ^= 1;
  }

  if (KW > 1) {
    // combine group 1's accumulators into group 0 through padded LDS.
    float* red = (float*)smem;
    if (g == 1) {
#pragma unroll
      for (int i = 0; i < WR; i++)
#pragma unroll
        for (int j = 0; j < 4; j++)
#pragma unroll
          for (int r = 0; r < 4; r++)
            red[(wm + i * 16 + quad * 4 + r) * 132 + wn + j * 16 + m] = acc[i][j][r];
    }
    __syncthreads();
    if (g == 0) {
#pragma unroll
      for (int i = 0; i < WR; i++)
#pragma unroll
        for (int j = 0; j < 4; j++)
#pragma unroll
          for (int r = 0; r < 4; r++)
            acc[i][j][r] += red[(wm + i * 16 + quad * 4 + r) * 132 + wn + j * 16 + m];
    }
  }

  if (g == 0) {
#pragma unroll
    for (int j = 0; j < 4; j++) {
      const int col = col0 + wn + j * 16 + m;
      const float bval = bias[col];
      if (MODE == 4) {
        const int sel = col >> 10;
        const int hh  = (col >> 6) & 15;
        const int f   = col & 63;
#pragma unroll
        for (int i = 0; i < WR; i++) {
          const int rowb = row0 + wm + i * 16 + quad * 4;
          if (sel < 2) {
            u16* dst = (u16*)(sel ? out2 : out);
#pragma unroll
            for (int r = 0; r < 4; r++)
              dst[((((size_t)hh << 12) + rowb + r) << 6) + f] = f2bf(acc[i][j][r] + bval);
          } else {
            uint2 o;
            o.x = pkbf(acc[i][j][0] + bval, acc[i][j][1] + bval);
            o.y = pkbf(acc[i][j][2] + bval, acc[i][j][3] + bval);
            *(uint2*)&((u16*)out3)[(((size_t)hh * 64 + f) << 12) + rowb] = o;
          }
        }
      } else {
#pragma unroll
        for (int i = 0; i < WR; i++) {
          const int rowb = row0 + wm + i * 16 + quad * 4;
#pragma unroll
          for (int r = 0; r < 4; r++) {
            float vv = acc[i][j][r] + bval;
            size_t idx = (size_t)(rowb + r) * N + col;
            if (MODE == 1) {
              ((u16*)out)[idx] = f2bf(fmaxf(vv, 0.f));
            } else if (MODE == 2) {
              ((float*)out)[idx] = vv + loadf(resid, idx, isf);
            } else if (MODE == 3) {
              float o = vv + ((const float*)resid)[idx];
              if (isf) ((float*)out)[idx] = o;
              else     ((u16*)out)[idx]   = f2bf(o);
            }
          }
        }
      }
    }
  }
}

// ---------------------------------------------------------------------------
// Flash attention, split-K, hybrid-MFMA transposed form. R19 structure
// (2-barrier JIT staging; R20's dbuf was neutral and reverted).
// R14: 128-q tiles, launch_bounds(512,4) -> 128-reg cap, zero spill.
// R21: T5 s_setprio(1) around QK and PV MFMA clusters (m191: +4-7% attn
// when independent blocks co-reside at different phases).
// ---------------------------------------------------------------------------
__global__ __launch_bounds__(512, 4) void attn_part(
    const u16* __restrict__ qh, const u16* __restrict__ kh,
    const u16* __restrict__ vT, u16* __restrict__ Opart,
    float* __restrict__ stats, u16* __restrict__ z) {
  const int combo = blockIdx.x;      // h*2 + b
  const int qt = blockIdx.y;         // 0..15 (128-row q-tiles)
  const int ci = blockIdx.z;         // 0..1 (1024-chunks)
  const int q0 = qt << 7;
  const int nc = (q0 + 128 + 1023) >> 10;
  if (ci >= nc) return;
  const int k_lo = ci << 10;
  const int k_hi = min(k_lo + 1024, q0 + 128);
  const int nsteps = (k_hi - k_lo + 127) >> 7;

  __shared__ u16 kS[128 * 72];       // K tile [tok][64+8 pad]; reused as O bounce
  __shared__ u16 vS[64 * 136];       // V^T tile [f][128 permuted + 8 pad]
  const int tid = threadIdx.x, L = tid & 63, w = tid >> 6;   // w 0..7
  const int m = L & 15, quad = L >> 4;
  const int h = combo >> 1, b = combo & 1;
  const size_t tb = (size_t)b * 2048;
  const size_t hbase = (size_t)h * 4096;
  const int qg = q0 + w * 16 + m;    // this lane's global q (column)

  // Q as 16x16x32 B-frags: lane n=q, k=feat quad*8+j (two 32-feat chunks)
  bf16x8 qb0, qb1;
  {
    const u16* qp = qh + ((hbase + tb + (size_t)qg) << 6) + quad * 8;
    qb0 = *(const bf16x8*)qp;
    qb1 = *(const bf16x8*)(qp + 32);
  }

  f32x4 zero4 = {0.f, 0.f, 0.f, 0.f};
  f32x4 O[4];                        // O^T: lane q, f = ft*16 + quad*4 + r
#pragma unroll
  for (int ft = 0; ft < 4; ft++) O[ft] = zero4;
  float mrow = -30000.f, lrow = 0.f;

  // staging: 512 thr, K tile 128x64 (1024 int4, 2 per thread),
  // V tile 64x128 (1024 int4, 2 per thread)
  const int krow[2] = { (0*512+tid) >> 3, (1*512+tid) >> 3 };
  const int kc = tid & 7;
  const int vf[2] = { (0*512+tid) >> 4, (1*512+tid) >> 4 };
  const int vc = tid & 15;
  // permuted V column bases for the two 4-elem halves of each int4
  const int vq = (vc & 1) << 1;             // quad base 2*(vc&1)
  const int vk4 = (vc >> 1) << 2;           // kt*4
  const int vc0 = (vq << 5) + vk4;          // quad*32 + kt*4
  const int vc1 = ((vq + 1) << 5) + vk4;

  for (int j = 0; j < nsteps; j++) {
    const int k0 = k_lo + (j << 7);
    // JIT load this step's K/V (issued before the barrier so the HBM
    // latency overlaps the barrier wait; regs are short-lived)
    int4 kr[2], vr[2];
#pragma unroll
    for (int i = 0; i < 2; i++) {
      kr[i] = *(const int4*)(kh + ((hbase + tb + k0 + krow[i]) << 6) + kc * 8);
      vr[i] = *(const int4*)(vT + (((size_t)h * 64 + vf[i]) << 12) + tb + k0 + vc * 8);
    }
    __syncthreads();                 // prev-step LDS consumers done
#pragma unroll
    for (int i = 0; i < 2; i++) {
      *(int4*)&kS[krow[i] * 72 + kc * 8] = kr[i];
      union { int4 v; s16x4 hh[2]; } tv; tv.v = vr[i];
      *(s16x4*)&vS[vf[i] * 136 + vc0] = tv.hh[0];
      *(s16x4*)&vS[vf[i] * 136 + vc1] = tv.hh[1];
    }
    __syncthreads();

    // two 64-token halves: sc[4] live instead of sc[8]
#pragma unroll
    for (int hs = 0; hs < 2; hs++) {
      const int kbase = k0 + hs * 64;
      f32x4 sc[4];
      // T5: favor this wave while it feeds the matrix pipe
      __builtin_amdgcn_s_setprio(1);
#pragma unroll
      for (int kt4 = 0; kt4 < 4; kt4++) {
        const int kt = hs * 4 + kt4;
        const u16* kp = &kS[(kt * 16 + m) * 72 + quad * 8];
        bf16x8 ka0 = *(const bf16x8*)kp;
        bf16x8 ka1 = *(const bf16x8*)(kp + 32);
        f32x4 t = zero4;
        t = __builtin_amdgcn_mfma_f32_16x16x32_bf16(ka0, qb0, t, 0, 0, 0);
        t = __builtin_amdgcn_mfma_f32_16x16x32_bf16(ka1, qb1, t, 0, 0, 0);
        sc[kt4] = t;
      }
      __builtin_amdgcn_s_setprio(0);
      if (kbase + 64 > q0) {   // touches diagonal region: causal mask
#pragma unroll
        for (int kt4 = 0; kt4 < 4; kt4++)
#pragma unroll
          for (int r = 0; r < 4; r++) {
            int ktok = kbase + kt4 * 16 + quad * 4 + r;
            if (ktok > qg) sc[kt4][r] = -30000.f;
          }
      }
      // per-lane max over 16 regs + 2 shuffles (q fixed per lane)
      float mx = sc[0][0];
#pragma unroll
      for (int kt4 = 0; kt4 < 4; kt4++)
#pragma unroll
        for (int r = 0; r < 4; r++) mx = fmaxf(mx, sc[kt4][r]);
      mx = fmaxf(mx, __shfl_xor(mx, 16, 64));
      mx = fmaxf(mx, __shfl_xor(mx, 32, 64));
      // defer-max (T13): only rescale when max grew by > 8 (exp2 domain)
      if (!__all(mx <= mrow + 8.f)) {
        float mnew = fmaxf(mrow, mx);
        float alpha = __builtin_amdgcn_exp2f(mrow - mnew);
        lrow *= alpha;
#pragma unroll
        for (int ft = 0; ft < 4; ft++) O[ft] *= alpha;
        mrow = mnew;
      }
      // P^T = exp2(S^T - m): pack to bf16 B-frags; accumulate l inline
      s16x4 pb[4];
      float sum = 0.f;
#pragma unroll
      for (int kt4 = 0; kt4 < 4; kt4++) {
        float e0 = __builtin_amdgcn_exp2f(sc[kt4][0] - mrow);
        float e1 = __builtin_amdgcn_exp2f(sc[kt4][1] - mrow);
        float e2 = __builtin_amdgcn_exp2f(sc[kt4][2] - mrow);
        float e3 = __builtin_amdgcn_exp2f(sc[kt4][3] - mrow);
        sum += (e0 + e1) + (e2 + e3);
        union { uint2 u; s16x4 hh; } pu;
        pu.u.x = pkbf(e0, e1);
        pu.u.y = pkbf(e2, e3);
        pb[kt4] = pu.hh;
      }
      sum += __shfl_xor(sum, 16, 64);
      sum += __shfl_xor(sum, 32, 64);
      lrow += sum;
      // O^T += V^T·P^T via 16x16x16 over this half's k-slots
      __builtin_amdgcn_s_setprio(1);
#pragma unroll
      for (int ft = 0; ft < 4; ft++) {
        const u16* vp = &vS[(ft * 16 + m) * 136 + quad * 32 + hs * 16];
#pragma unroll
        for (int p2 = 0; p2 < 2; p2++) {
          union { bf16x8 v; s16x4 hh[2]; } u;
          u.v = *(const bf16x8*)(vp + p2 * 8);
          O[ft] = mfma16(u.hh[0], pb[2 * p2],     O[ft]);
          O[ft] = mfma16(u.hh[1], pb[2 * p2 + 1], O[ft]);
        }
      }
      __builtin_amdgcn_s_setprio(0);
    }
  }

  // nc==1: normalize in-kernel (diagonal guarantees lrow > 0)
  if (nc == 1) {
    float inv = 1.f / lrow;
#pragma unroll
    for (int ft = 0; ft < 4; ft++) O[ft] *= inv;
  }

  // O^T -> LDS bounce (kS reused, 128 rows x 64f) -> coalesced global stores
  __syncthreads();
#pragma unroll
  for (int ft = 0; ft < 4; ft++) {
    union { uint2 u; s16x4 hh; } o4;
    o4.u.x = pkbf(O[ft][0], O[ft][1]);
    o4.u.y = pkbf(O[ft][2], O[ft][3]);
    *(s16x4*)&kS[(w * 16 + m) * 72 + ft * 16 + quad * 4] = o4.hh;
  }
  __syncthreads();
  if (nc == 1) {
    // direct z write: [tok][1024] layout, this head's 64-col stripe
    u16* zp = z + ((tb + (size_t)q0) << 10) + h * 64;
#pragma unroll
    for (int it = 0; it < 2; it++) {
      int idx = it * 512 + tid;
      int row = idx >> 3, c = idx & 7;
      *(int4*)&zp[((size_t)row << 10) + c * 8] = *(const int4*)&kS[row * 72 + c * 8];
    }
  } else {
    const int slot = (combo * 16 + qt) * 2 + ci;
    u16* op = Opart + ((size_t)slot << 13);
#pragma unroll
    for (int it = 0; it < 2; it++) {
      int idx = it * 512 + tid;
      int row = idx >> 3, c = idx & 7;
      *(int4*)&op[row * 64 + c * 8] = *(const int4*)&kS[row * 72 + c * 8];
    }
    if (quad == 0) {
      stats[slot * 256 + w * 16 + m]       = mrow;
      stats[slot * 256 + 128 + w * 16 + m] = lrow;
    }
  }
}

// merge partials -> z [t][1024]; only qt>=8 tiles (nc==2) reach here. 512 thr.
__global__ __launch_bounds__(512) void attn_merge(
    const u16* __restrict__ Opart, const float* __restrict__ stats,
    u16* __restrict__ z) {
  const int combo = blockIdx.x, qt = 8 + blockIdx.y;
  const int h = combo >> 1, b = combo & 1;
  const int q0 = qt << 7;
  const int tid = threadIdx.x;
  const int t = tid >> 2, f0 = (tid & 3) << 4;   // t 0..127
  const int slot0 = (combo * 16 + qt) * 2;
  float M = fmaxf(stats[slot0 * 256 + t], stats[(slot0 + 1) * 256 + t]);
  float acc[16];
#pragma unroll
  for (int e = 0; e < 16; e++) acc[e] = 0.f;
  float ltot = 0.f;
#pragma unroll
  for (int ci = 0; ci < 2; ci++) {
    float mi = stats[(slot0 + ci) * 256 + t];
    float li = stats[(slot0 + ci) * 256 + 128 + t];
    float wgt = exp2f(mi - M);
    ltot += wgt * li;
    const u16* op = Opart + (((size_t)(slot0 + ci)) << 13) + t * 64 + f0;
    union { int4 v; u16 u[8]; } a0, a1;
    a0.v = *(const int4*)op;
    a1.v = *(const int4*)(op + 8);
#pragma unroll
    for (int e = 0; e < 8; e++) {
      acc[e]     += wgt * bf2f(a0.u[e]);
      acc[8 + e] += wgt * bf2f(a1.u[e]);
    }
  }
  float inv = 1.f / ltot;
  union { int4 v; u16 u[8]; } o0, o1;
#pragma unroll
  for (int e = 0; e < 8; e++) {
    o0.u[e] = f2bf(acc[e] * inv);
    o1.u[e] = f2bf(acc[8 + e] * inv);
  }
  size_t tok = (size_t)b * 2048 + q0 + t;
  *(int4*)&z[tok * 1024 + h * 64 + f0]     = o0.v;
  *(int4*)&z[tok * 1024 + h * 64 + f0 + 8] = o1.v;
}

// ---------------------------------------------------------------------------
extern "C" void kernel_launch(void* const* d_in, const int* in_sizes, int n_in,
                              void* d_out, int out_size, void* d_ws, size_t ws_size,
                              hipStream_t stream) {
  (void)in_sizes; (void)n_in; (void)out_size; (void)ws_size;
  const void* resid_pre = d_in[0];
  const void* ln1_w = d_in[1];
  const void* ln1_b = d_in[2];
  const void* W_Q   = d_in[3];
  const void* b_Q   = d_in[4];
  const void* W_K   = d_in[5];
  const void* b_K   = d_in[6];
  const void* W_V   = d_in[7];
  const void* b_V   = d_in[8];
  const void* W_O   = d_in[9];
  const void* b_O   = d_in[10];
  const void* ln2_w = d_in[11];
  const void* ln2_b = d_in[12];
  const void* W_in  = d_in[13];
  const void* b_in  = d_in[14];
  const void* W_out = d_in[15];
  const void* b_out = d_in[16];

  char* p = (char*)d_ws;
  auto alloc = [&](size_t bytes) {
    char* r = p; p += (bytes + 255) & ~(size_t)255; return (void*)r;
  };
  int*   flag      = (int*)  alloc(256);
  u16*   WqkvT     = (u16*)  alloc(3072ull * 1024 * 2);
  u16*   WoT       = (u16*)  alloc(1024ull * 1024 * 2);
  u16*   WinT      = (u16*)  alloc(4096ull * 1024 * 2);
  u16*   WoutT     = (u16*)  alloc(1024ull * 4096 * 2);
  float* biases    = (float*)alloc(9216 * 4);
  u16*   xn        = (u16*)  alloc(4096ull * 1024 * 2);  // reused as z
  u16*   q_hm      = (u16*)  alloc(16ull * 4096 * 64 * 2);
  u16*   k_hm      = (u16*)  alloc(16ull * 4096 * 64 * 2);
  u16*   vTws      = (u16*)  alloc(16ull * 64 * 4096 * 2);
  float* resid_mid = (float*)alloc(4096ull * 1024 * 4);
  u16*   h2        = (u16*)  alloc(4096ull * 1024 * 2);  // attn stats before ln2
  u16*   act       = (u16*)  alloc(4096ull * 4096 * 2);  // attn partials before MLP
  float* part3     = (float*)alloc(4096ull * 1024 * 4);  // split-K chunk 3
  u16*   z = xn;
  u16*   Opart = act;              // 1024 slots x 16 KB = 16 MB (< 32 MB)
  float* stats = (float*)h2;       // 1024 slots x 256 fp32 = 1 MB < 8 MB
  // R19 split-K partial buffers (each exactly 16 MB, DEAD by final gemm):
  //   part0 = WqkvT(6MB)+WoT(2MB)+WinT(8MB)  [contiguous, ends at WoutT]
  //   part1 = xn(8MB)+q_hm(8MB)
  //   part2 = k_hm(8MB)+vTws(8MB)            [ends exactly at resid_mid]
  //   part3 = fresh 16MB alloc
  float* part0 = (float*)WqkvT;
  float* part1 = (float*)xn;
  float* part2 = (float*)k_hm;

  detect_dtype<<<1, 256, 0, stream>>>((const unsigned int*)resid_pre, flag);

  pack_qkv_tiled<<<dim3(16, 48), 256, 0, stream>>>(flag, W_Q, W_K, W_V, WqkvT);
  transpose_tiled<<<dim3(16, 16), 256, 0, stream>>>(flag, W_O,   WoT,   1024, 1024);
  transpose_tiled<<<dim3(64, 16), 256, 0, stream>>>(flag, W_in,  WinT,  1024, 4096);
  transpose_tiled<<<dim3(16, 64), 256, 0, stream>>>(flag, W_out, WoutT, 4096, 1024);
  pack_biases<<<36, 256, 0, stream>>>(flag, b_Q, b_K, b_V, b_O, b_in, b_out, biases);

  ln_fwd<0><<<4096, 256, 0, stream>>>(flag, resid_pre, ln1_w, ln1_b, xn);
  // qkv -> head-major q/k + transposed v. grid: 8 XCD x SH=4 rows x 24 cols
  gemm_bt<4, 128, 1><<<768, 256, 0, stream>>>(
      flag, xn, WqkvT, biases, nullptr, q_hm, k_hm, vTws, 4096, 3072, 1024, 2);
  // split-K causal flash attention (128-q tiles, 1024-chunks) -> z
  attn_part<<<dim3(32, 16, 2), 512, 0, stream>>>(q_hm, k_hm, vTws, Opart, stats, z);
  attn_merge<<<dim3(32, 8), 512, 0, stream>>>(Opart, stats, z);
  // resid_mid = resid_pre + z @ W_O + b_O   (fp32). 8 XCD x SH=8 x 8 cols,
  // in-block split-K (512 thr), gload_lds dbuf staging
  gemm_bt<2, 64, 2><<<512, 512, 0, stream>>>(
      flag, z, WoT, biases + 3072, resid_pre, resid_mid, nullptr, nullptr, 4096, 1024, 1024, 3);
  ln_fwd<1><<<4096, 256, 0, stream>>>(flag, resid_mid, ln2_w, ln2_b, h2);
  // act = relu(h2 @ W_in + b_in). 256^2-tile 4-phase counted-vmcnt template.
  gemm256<0><<<256, 512, 0, stream>>>(h2, WinT, biases + 4096, act,
                                      nullptr, nullptr, nullptr, nullptr,
                                      4096, 4096, 1024);
  // out = resid_mid + act @ W_out + b_out. SPLIT-K=4 on the 256^2
  // template (256 blocks = 1/CU, nt=16) -> fp32 partials -> fused reduce.
  gemm256<1><<<256, 512, 0, stream>>>(act, WoutT, nullptr, nullptr,
                                      part0, part1, part2, part3,
                                      4096, 1024, 4096);
  reduce_sk<<<4096, 256, 0, stream>>>(flag, part0, part1, part2, part3,
                                      biases + 8192, resid_mid, d_out);
}